// Round 8
// baseline (478.294 us; speedup 1.0000x reference)
//
#include <hip/hip_runtime.h>
#include <hip/hip_fp16.h>
#include <math.h>

#define Hh 160
#define Ww 160
#define Cc 128
#define HW 25600
#define NPIX 102400   // N*H*W, N=4

typedef __attribute__((ext_vector_type(8))) _Float16 half8;
typedef __attribute__((ext_vector_type(4))) float f32x4;
typedef __attribute__((ext_vector_type(4))) unsigned int u32x4;

union h2u { __half2 h; unsigned int u; };
union v16 { u32x4 u; half8 h; };

// ws byte layout (all 16B aligned)
#define WS_OFFS  0u            // 9*102400*2*4 = 7372800  [k][p][2] fp32
#define WS_WA    7372800u      // 9*128*128*2 = 294912  fp16 [k][o][c]
#define WS_WP16  7667712u      // 16*1152*2 = 36864     fp16 [m][tap*128+c]
#define WS_GSUM  7704576u      // 512
#define WS_GSQ   7705088u      // 512
#define WS_XT    7705600u      // 102400*128*2 = 26214400 (fp16 NHWC)
#define WS_RAW   33920000u     // 4*128*25600*4 = 52428800

// --------------------------------------------------------------------------
// Kernel W: w_dcn -> wA fp16 [k][o][c]; pack tm/tr weights -> wP16 [m][k*128+c]
// (m: 0-3 = tm rows, 4-5 = tr rows, 6-15 = zero pad for M=16 MFMA)
__global__ void wtrans_kernel(const float* __restrict__ w_dcn,
                              const float* __restrict__ w_tm,
                              const float* __restrict__ w_tr,
                              unsigned short* __restrict__ wA,
                              unsigned short* __restrict__ wP16) {
    int idx = blockIdx.x * 256 + threadIdx.x;
    if (idx < 16 * 1152) {
        int m = idx / 1152;
        int r = idx - m * 1152;
        int tap = r >> 7;
        int c = r & 127;
        float v = 0.f;
        if (m < 4) v = w_tm[(m * 128 + c) * 9 + tap];
        else if (m < 6) v = w_tr[((m - 4) * 128 + c) * 9 + tap];
        wP16[idx] = __half_as_ushort(__float2half(v));
    }
    if (idx >= 9 * 128 * 128) return;
    int k = idx >> 14;
    int o = (idx >> 7) & 127;
    int c = idx & 127;
    wA[idx] = __half_as_ushort(__float2half(w_dcn[(o * 128 + c) * 9 + k]));
}

// --------------------------------------------------------------------------
// Kernel X: NCHW fp32 -> NHWC fp16 transpose via LDS tile
__global__ void __launch_bounds__(256) xpose_kernel(
    const float* __restrict__ x, unsigned short* __restrict__ xT) {
    __shared__ float L[128 * 65];
    int b = blockIdx.x;
    int n = b / 400;
    int px0 = (b - n * 400) * 64;
    int t = threadIdx.x;
    const float* xn = x + (size_t)n * Cc * HW + px0;
#pragma unroll
    for (int i = 0; i < 32; ++i) {
        int idx = i * 256 + t;
        int ch = idx >> 6;
        int pxl = idx & 63;
        L[ch * 65 + pxl] = xn[(size_t)ch * HW + pxl];
    }
    __syncthreads();
    unsigned short* dst = xT + ((size_t)n * HW + px0) * 128;
#pragma unroll
    for (int j = 0; j < 16; ++j) {
        int idx = j * 256 + t;
        int pxl = idx >> 6;
        int cp = idx & 63;
        h2u cv;
        cv.h = __floats2half2_rn(L[(2 * cp) * 65 + pxl],
                                 L[(2 * cp + 1) * 65 + pxl]);
        *(unsigned int*)(dst + (size_t)pxl * 128 + cp * 2) = cv.u;
    }
}

// --------------------------------------------------------------------------
// Kernel A: offs conv as MFMA GEMM. M=16 (6 live: tm0-3,tr0,tr1), K=1152
// (9 static taps x 128c from xT with zero-mask), N=16 px per wave.
// C layout: lane(quad,l15) holds rows quad*4+e for pixel l15 -> shfl to
// gather a4,a5 onto quad0, emit (py,px) x 9 taps.
__global__ void __launch_bounds__(256) offs_kernel(
    const unsigned short* __restrict__ xT, const unsigned short* __restrict__ wP16,
    const float* __restrict__ b_tm, const float* __restrict__ b_tr,
    float* __restrict__ offs2) {
    int t = threadIdx.x;
    int lane = t & 63, wid = t >> 6;
    int quad = lane >> 4, l15 = lane & 15;
    int bid = blockIdx.x;
    int blk = (bid & 7) * 200 + (bid >> 3);   // XCD-contiguous px slices
    int pxb = blk * 64 + wid * 16;
    int n = pxb / HW;
    int hw0 = pxb - n * HW;
    int hw = hw0 + l15;
    int h = hw / Ww;
    int w = hw - h * Ww;
    const char* xb = (const char*)(xT + (size_t)n * HW * 128);
    const char* Wp = (const char*)wP16;
    f32x4 acc = (f32x4)0.f;
#pragma unroll
    for (int tap = 0; tap < 9; ++tap) {
        int dy = tap / 3 - 1, dx = tap % 3 - 1;
        int yy = h + dy, xx = w + dx;
        bool valid = ((unsigned)yy < (unsigned)Hh) && ((unsigned)xx < (unsigned)Ww);
        int cell = (valid ? yy : 0) * Ww + (valid ? xx : 0);
        __half2 m2 = __float2half2_rn(valid ? 1.f : 0.f);
        const char* cbp = xb + ((size_t)cell << 8) + quad * 16;
#pragma unroll
        for (int q = 0; q < 4; ++q) {
            v16 bv;
            bv.u = *(const u32x4*)(cbp + q * 64);
#pragma unroll
            for (int e = 0; e < 4; ++e) {
                h2u xv; xv.u = bv.u[e];
                xv.h = __hmul2(xv.h, m2);
                bv.u[e] = xv.u;
            }
            half8 av = *(const half8*)(Wp +
                        ((size_t)l15 * 1152 + tap * 128 + q * 32 + quad * 8) * 2);
            acc = __builtin_amdgcn_mfma_f32_16x16x32_f16(av, bv.h, acc, 0, 0, 0);
        }
    }
    float a4 = __shfl(acc[0], 16 + l15);
    float a5 = __shfl(acc[1], 16 + l15);
    if (quad == 0) {
        int p = pxb + l15;
        float a0 = acc[0] + b_tm[0], a1 = acc[1] + b_tm[1];
        float a2 = acc[2] + b_tm[2], a3 = acc[3] + b_tm[3];
        a4 += b_tr[0]; a5 += b_tr[1];
#pragma unroll
        for (int k = 0; k < 9; ++k) {
            float r0 = (float)(k / 3) - 1.f;
            float r1 = (float)(k % 3) - 1.f;
            float2 st;
            st.x = (float)h + a0 * r0 + a1 * r1 + a4;
            st.y = (float)w + a2 * r0 + a3 * r1 + a5;
            *(float2*)(offs2 + ((size_t)k * NPIX + p) * 2) = st;
        }
    }
}

// --------------------------------------------------------------------------
// Kernel D: BARRIER-FREE fused deformable conv. Wave = 32 px x 128 o.
// B-frags gathered directly into registers (lane l15 = pixel, quad/q pick the
// 16B channel segment -> exactly the MFMA B layout), combined with pk_fma_f16.
// A-frags from global wA[k][o][c] (L1-hot, shared by all waves). No LDS in
// the K-loop, no __syncthreads until the epilogue GN reduction.
__global__ void __launch_bounds__(256, 3) dcn2_kernel(
    const unsigned short* __restrict__ xT, const float* __restrict__ offs2,
    const unsigned short* __restrict__ wA, float* __restrict__ raw,
    float* __restrict__ gsum, float* __restrict__ gsq) {
    __shared__ float red[4][64];
    int t = threadIdx.x;
    int lane = t & 63, wid = t >> 6;
    int quad = lane >> 4, l15 = lane & 15;
    int bid = blockIdx.x;
    int blk = (bid & 7) * 100 + (bid >> 3);   // XCD-contiguous px slices
    int px0b = blk * 128;
    int n = px0b / HW;
    int hw0 = px0b - n * HW + wid * 32;
    int px0 = px0b + wid * 32;
    const char* xb = (const char*)(xT + (size_t)n * HW * 128);
    const char* Ag = (const char*)wA;

    f32x4 acc[8][2];
#pragma unroll
    for (int i = 0; i < 8; ++i) {
        acc[i][0] = (f32x4)0.f;
        acc[i][1] = (f32x4)0.f;
    }

#pragma unroll 1
    for (int k = 0; k < 9; ++k) {
        const char* cb[2][4];
        __half2 Wc[2][4];
#pragma unroll
        for (int j = 0; j < 2; ++j) {
            int p = px0 + j * 16 + l15;
            float2 pc = *(const float2*)(offs2 + ((size_t)k * NPIX + p) * 2);
            float py = pc.x, px = pc.y;
            float y0f = floorf(py), x0f = floorf(px);
            float fy = py - y0f, fx = px - x0f;
            int y0 = (int)y0f, xi0 = (int)x0f;
            int y1 = y0 + 1, xi1 = xi0 + 1;
            float w00 = (1.f - fy) * (1.f - fx), w01 = (1.f - fy) * fx;
            float w10 = fy * (1.f - fx), w11 = fy * fx;
            bool vy0 = (unsigned)y0 < (unsigned)Hh, vy1 = (unsigned)y1 < (unsigned)Hh;
            bool vx0 = (unsigned)xi0 < (unsigned)Ww, vx1 = (unsigned)xi1 < (unsigned)Ww;
            w00 = (vy0 && vx0) ? w00 : 0.f;
            w01 = (vy0 && vx1) ? w01 : 0.f;
            w10 = (vy1 && vx0) ? w10 : 0.f;
            w11 = (vy1 && vx1) ? w11 : 0.f;
            int cy0 = vy0 ? y0 : 0, cy1 = vy1 ? y1 : 0;
            int cx0 = vx0 ? xi0 : 0, cx1 = vx1 ? xi1 : 0;
            cb[j][0] = xb + ((size_t)(cy0 * Ww + cx0) << 8) + quad * 16;
            cb[j][1] = xb + ((size_t)(cy0 * Ww + cx1) << 8) + quad * 16;
            cb[j][2] = xb + ((size_t)(cy1 * Ww + cx0) << 8) + quad * 16;
            cb[j][3] = xb + ((size_t)(cy1 * Ww + cx1) << 8) + quad * 16;
            Wc[j][0] = __float2half2_rn(w00);
            Wc[j][1] = __float2half2_rn(w01);
            Wc[j][2] = __float2half2_rn(w10);
            Wc[j][3] = __float2half2_rn(w11);
        }
        v16 b[2][4];
#pragma unroll
        for (int q = 0; q < 4; ++q)
#pragma unroll
            for (int j = 0; j < 2; ++j) {
                u32x4 v0 = *(const u32x4*)(cb[j][0] + q * 64);
                u32x4 v1 = *(const u32x4*)(cb[j][1] + q * 64);
                u32x4 v2 = *(const u32x4*)(cb[j][2] + q * 64);
                u32x4 v3 = *(const u32x4*)(cb[j][3] + q * 64);
#pragma unroll
                for (int e = 0; e < 4; ++e) {
                    h2u A, B, C, D, O;
                    A.u = v0[e]; B.u = v1[e]; C.u = v2[e]; D.u = v3[e];
                    __half2 r = __hmul2(Wc[j][3], D.h);
                    r = __hfma2(Wc[j][2], C.h, r);
                    r = __hfma2(Wc[j][1], B.h, r);
                    r = __hfma2(Wc[j][0], A.h, r);
                    O.h = r;
                    b[j][q].u[e] = O.u;
                }
            }
#pragma unroll
        for (int q = 0; q < 4; ++q) {
            int koff = ((k * 128 + l15) << 8) + q * 64 + quad * 16;
#pragma unroll
            for (int i = 0; i < 8; ++i) {
                half8 av = *(const half8*)(Ag + koff + (i << 12));
                acc[i][0] = __builtin_amdgcn_mfma_f32_16x16x32_f16(
                    av, b[0][q].h, acc[i][0], 0, 0, 0);
                acc[i][1] = __builtin_amdgcn_mfma_f32_16x16x32_f16(
                    av, b[1][q].h, acc[i][1], 0, 0, 0);
            }
        }
    }

    // ---- epilogue: raw out + GN block reduction + atomics ----
    size_t rbase = ((size_t)n * Cc) * HW + hw0;
#pragma unroll
    for (int i = 0; i < 8; ++i) {
        float s_i = 0.f, q_i = 0.f;
#pragma unroll
        for (int j = 0; j < 2; ++j)
#pragma unroll
            for (int e = 0; e < 4; ++e) {
                int o = i * 16 + quad * 4 + e;
                float v = acc[i][j][e];
                raw[rbase + (size_t)o * HW + j * 16 + l15] = v;
                s_i += v;
                q_i += v * v;
            }
#pragma unroll
        for (int m = 1; m < 16; m <<= 1) {
            s_i += __shfl_xor(s_i, m);
            q_i += __shfl_xor(q_i, m);
        }
        if (l15 == 0) {
            red[wid][i * 4 + quad] = s_i;
            red[wid][32 + i * 4 + quad] = q_i;
        }
    }
    __syncthreads();
    if (t < 64) {
        float tot = red[0][t] + red[1][t] + red[2][t] + red[3][t];
        int g = t & 31;
        if (t < 32) atomicAdd(&gsum[n * 32 + g], tot);
        else        atomicAdd(&gsq[n * 32 + g], tot);
    }
}

// --------------------------------------------------------------------------
// Kernel C: GroupNorm finalize + residual + ReLU (float4)
__global__ void __launch_bounds__(256) finish_kernel(
    const float* __restrict__ raw, const float* __restrict__ x,
    const float* __restrict__ gsum, const float* __restrict__ gsq,
    const float* __restrict__ gamma, const float* __restrict__ beta,
    float* __restrict__ out) {
    int i = blockIdx.x * 256 + threadIdx.x;
    int e = i * 4;
    int n = e / (Cc * HW);
    int rem = e - n * (Cc * HW);
    int c = rem / HW;
    int g = c >> 2;
    const float inv = 1.f / 102400.f;
    float mu = gsum[n * 32 + g] * inv;
    float var = gsq[n * 32 + g] * inv - mu * mu;
    float rs = rsqrtf(var + 1e-5f);
    float sc = gamma[c] * rs;
    float sh = beta[c] - mu * sc;
    float4 v = *(const float4*)&raw[e];
    float4 xv = *(const float4*)&x[e];
    float4 r;
    r.x = fmaxf(v.x * sc + sh + xv.x, 0.f);
    r.y = fmaxf(v.y * sc + sh + xv.y, 0.f);
    r.z = fmaxf(v.z * sc + sh + xv.z, 0.f);
    r.w = fmaxf(v.w * sc + sh + xv.w, 0.f);
    *(float4*)&out[e] = r;
}

// --------------------------------------------------------------------------
extern "C" void kernel_launch(void* const* d_in, const int* in_sizes, int n_in,
                              void* d_out, int out_size, void* d_ws, size_t ws_size,
                              hipStream_t stream) {
    const float* x      = (const float*)d_in[0];
    const float* w_tm   = (const float*)d_in[1];
    const float* b_tm   = (const float*)d_in[2];
    const float* w_tr   = (const float*)d_in[3];
    const float* b_tr   = (const float*)d_in[4];
    const float* w_dcn  = (const float*)d_in[5];
    const float* gamma  = (const float*)d_in[6];
    const float* beta   = (const float*)d_in[7];
    char* ws = (char*)d_ws;
    float*          offs2 = (float*)(ws + WS_OFFS);
    unsigned short* wA    = (unsigned short*)(ws + WS_WA);
    unsigned short* wP16  = (unsigned short*)(ws + WS_WP16);
    float*          gsum  = (float*)(ws + WS_GSUM);
    float*          gsq   = (float*)(ws + WS_GSQ);
    unsigned short* xT    = (unsigned short*)(ws + WS_XT);
    float*          raw   = (float*)(ws + WS_RAW);
    float* out = (float*)d_out;

    (void)hipMemsetAsync(gsum, 0, 1024, stream);   // gsum + gsq
    wtrans_kernel<<<576, 256, 0, stream>>>(w_dcn, w_tm, w_tr, wA, wP16);
    xpose_kernel<<<1600, 256, 0, stream>>>(x, xT);
    offs_kernel<<<1600, 256, 0, stream>>>(xT, wP16, b_tm, b_tr, offs2);
    dcn2_kernel<<<800, 256, 0, stream>>>(xT, offs2, wA, raw, gsum, gsq);
    finish_kernel<<<12800, 256, 0, stream>>>(raw, x, gsum, gsq, gamma, beta, out);
}